// Round 1
// baseline (720.044 us; speedup 1.0000x reference)
//
#include <hip/hip_runtime.h>

// ---------------------------------------------------------------------------
// GraphSAGE 3-layer forward. Round 6:
//  - counts zeroed via hipMemsetAsync (graph-capturable memset node)
//  - sage_hist folded into sage_prep (atomic blocks overlap BW-bound cast)
//  - GEMM: BK=64, LDS 36.9 KB (4 blocks/CU), LDS-repack coalesced epilogue
//  - gather0: 8-edge unroll (4 independent row loads per 32-lane half)
//  Harness floor (ws poison + input restore) ~460-490 us of dur_us is fixed.
// ---------------------------------------------------------------------------

typedef __bf16 bf16x8 __attribute__((ext_vector_type(8)));
typedef float f32x4 __attribute__((ext_vector_type(4)));

static __device__ __forceinline__ unsigned short f32_to_bf16(float f) {
    unsigned u = __float_as_uint(f);
    u += 0x7fffu + ((u >> 16) & 1u);   // round-nearest-even
    return (unsigned short)(u >> 16);
}
static __device__ __forceinline__ float bf16lo(unsigned u) { return __uint_as_float(u << 16); }
static __device__ __forceinline__ float bf16hi(unsigned u) { return __uint_as_float(u & 0xffff0000u); }

// ---------------- fused prep: cast x[:51200] to bf16, build WT0/1/2, hist ----
// counts must be pre-zeroed (hipMemsetAsync before this kernel).
__global__ void sage_prep(const float* __restrict__ x, unsigned short* __restrict__ xcast,
                          const float* __restrict__ Ws0, const float* __restrict__ Wn0,
                          const float* __restrict__ Ws1, const float* __restrict__ Wn1,
                          const float* __restrict__ Ws2, const float* __restrict__ Wn2,
                          unsigned short* __restrict__ WT0, unsigned short* __restrict__ WT1,
                          unsigned short* __restrict__ WT2,
                          const int* __restrict__ d0, int* __restrict__ c0,
                          const int* __restrict__ d1, int* __restrict__ c1,
                          const int* __restrict__ d2, int* __restrict__ c2) {
    const int b = blockIdx.x;
    if (b < 6400) {                       // cast: 51200*128 floats, 1 float4/thread
        int i = b * 256 + threadIdx.x;
        float4 v = ((const float4*)x)[i];
        uint2 o;
        o.x = (unsigned)f32_to_bf16(v.x) | ((unsigned)f32_to_bf16(v.y) << 16);
        o.y = (unsigned)f32_to_bf16(v.z) | ((unsigned)f32_to_bf16(v.w) << 16);
        ((uint2*)xcast)[i] = o;
    } else if (b < 6656) {                // WT0: [256][256], K1=128
        int idx = (b - 6400) * 256 + threadIdx.x;
        int n = idx >> 8, k = idx & 255;
        float v = (k < 128) ? Ws0[(size_t)k * 256 + n] : Wn0[(size_t)(k - 128) * 256 + n];
        WT0[idx] = f32_to_bf16(v);
    } else if (b < 7168) {                // WT1: [256][512], K1=256
        int idx = (b - 6656) * 256 + threadIdx.x;
        int n = idx >> 9, k = idx & 511;
        float v = (k < 256) ? Ws1[(size_t)k * 256 + n] : Wn1[(size_t)(k - 256) * 256 + n];
        WT1[idx] = f32_to_bf16(v);
    } else if (b < 7262) {                // WT2: [47][512], K1=256
        int idx = (b - 7168) * 256 + threadIdx.x;
        int n = idx >> 9, k = idx & 511;
        float v = (k < 256) ? Ws2[(size_t)k * 47 + n] : Wn2[(size_t)(k - 256) * 47 + n];
        WT2[idx] = f32_to_bf16(v);
    } else if (b < 10262) {               // hist layer 0 (768000 edges)
        atomicAdd(&c0[d0[(b - 7262) * 256 + threadIdx.x]], 1);
    } else if (b < 10462) {               // hist layer 1 (51200 edges)
        atomicAdd(&c1[d1[(b - 10262) * 256 + threadIdx.x]], 1);
    } else {                              // hist layer 2 (5120 edges)
        atomicAdd(&c2[d2[(b - 10462) * 256 + threadIdx.x]], 1);
    }
}

// ---------------- fused scan: block b scans layer b (1024 threads) ----------------
__global__ void sage_scan(const int* __restrict__ c0, int* __restrict__ o0, int* __restrict__ u0,
                          const int* __restrict__ c1, int* __restrict__ o1, int* __restrict__ u1,
                          const int* __restrict__ c2, int* __restrict__ o2, int* __restrict__ u2) {
    const int* counts; int* offsets; int* cursor; int n;
    if (blockIdx.x == 0)      { counts = c0; offsets = o0; cursor = u0; n = 51200; }
    else if (blockIdx.x == 1) { counts = c1; offsets = o1; cursor = u1; n = 5120; }
    else                      { counts = c2; offsets = o2; cursor = u2; n = 1024; }

    __shared__ int wsum[16];
    __shared__ int wbase[16];
    __shared__ int s_carry;
    const int tid = threadIdx.x;
    const int lane = tid & 63;
    const int wid = tid >> 6;
    if (tid == 0) s_carry = 0;
    __syncthreads();

    for (int base = 0; base < n; base += 8192) {
        int idx = base + tid * 8;
        int v[8];
#pragma unroll
        for (int u = 0; u < 8; ++u) v[u] = (idx + u < n) ? counts[idx + u] : 0;
        int tsum = 0;
#pragma unroll
        for (int u = 0; u < 8; ++u) { int t = v[u]; v[u] = tsum; tsum += t; }
        int incl = tsum;
#pragma unroll
        for (int d = 1; d < 64; d <<= 1) {
            int t = __shfl_up(incl, d, 64);
            if (lane >= d) incl += t;
        }
        int wexcl = incl - tsum;
        if (lane == 63) wsum[wid] = incl;
        __syncthreads();                       // B1: wsum ready
        int carry = s_carry;
        __syncthreads();                       // B2: carry reads done
        if (tid < 64) {
            int s = (lane < 16) ? wsum[lane] : 0;
            int inc = s;
#pragma unroll
            for (int d = 1; d < 16; d <<= 1) {
                int t = __shfl_up(inc, d, 64);
                if (lane >= d) inc += t;
            }
            if (lane < 16) wbase[lane] = carry + inc - s;
            if (lane == 15) s_carry = carry + inc;
        }
        __syncthreads();                       // B3: wbase ready
        int pre = wbase[wid] + wexcl;
#pragma unroll
        for (int u = 0; u < 8; ++u)
            if (idx + u < n) { int o = pre + v[u]; offsets[idx + u] = o; cursor[idx + u] = o; }
        __syncthreads();                       // protect wsum/s_carry for next iter
    }
    if (tid == 0) offsets[n] = s_carry;
}

// ---------------- fused fill (3 layers) ----------------
__global__ void sage_fill(const int* __restrict__ s0, const int* __restrict__ d0,
                          int* __restrict__ u0, int* __restrict__ r0,
                          const int* __restrict__ s1, const int* __restrict__ d1,
                          int* __restrict__ u1, int* __restrict__ r1,
                          const int* __restrict__ s2, const int* __restrict__ d2,
                          int* __restrict__ u2, int* __restrict__ r2) {
    const int b = blockIdx.x;
    if (b < 3000) {
        int i = b * 256 + threadIdx.x;
        int pos = atomicAdd(&u0[d0[i]], 1);
        r0[pos] = s0[i];
    } else if (b < 3200) {
        int i = (b - 3000) * 256 + threadIdx.x;
        int pos = atomicAdd(&u1[d1[i]], 1);
        r1[pos] = s1[i];
    } else {
        int i = (b - 3200) * 256 + threadIdx.x;
        int pos = atomicAdd(&u2[d2[i]], 1);
        r2[pos] = s2[i];
    }
}

// ---------------- gather, feat=128 fp32 src -> bf16 out ----------------
// One wave per dst row; 32 lanes x float4 cover a row; each half takes up to 4
// edges per iteration (8 row-loads in flight per wave).
__global__ void sage_gather0(const float* __restrict__ x, const int* __restrict__ csr,
                             const int* __restrict__ off, unsigned short* __restrict__ out,
                             int n_dst) {
    int row = (blockIdx.x * 256 + threadIdx.x) >> 6;
    if (row >= n_dst) return;
    const int lane = threadIdx.x & 63;
    const int half = lane >> 5;
    const int fl = lane & 31;
    const int beg = off[row], end = off[row + 1];
    const float4* hp = (const float4*)x + fl;   // lane-fixed column offset
    float4 accA = make_float4(0.f, 0.f, 0.f, 0.f);
    float4 accB = make_float4(0.f, 0.f, 0.f, 0.f);
    int i = beg;
    for (; i + 7 < end; i += 8) {          // half0 {i,i+2,i+4,i+6}, half1 {+1,...}
        int s0 = csr[i + half];
        int s1 = csr[i + 2 + half];
        int s2 = csr[i + 4 + half];
        int s3 = csr[i + 6 + half];
        float4 v0 = hp[(size_t)s0 * 32];
        float4 v1 = hp[(size_t)s1 * 32];
        float4 v2 = hp[(size_t)s2 * 32];
        float4 v3 = hp[(size_t)s3 * 32];
        accA.x += v0.x; accA.y += v0.y; accA.z += v0.z; accA.w += v0.w;
        accB.x += v1.x; accB.y += v1.y; accB.z += v1.z; accB.w += v1.w;
        accA.x += v2.x; accA.y += v2.y; accA.z += v2.z; accA.w += v2.w;
        accB.x += v3.x; accB.y += v3.y; accB.z += v3.z; accB.w += v3.w;
    }
    for (; i + 1 < end; i += 2) {
        int s = csr[i + half];
        float4 v = hp[(size_t)s * 32];
        accA.x += v.x; accA.y += v.y; accA.z += v.z; accA.w += v.w;
    }
    if (i < end && half == 0) {
        int s = csr[i];
        float4 v = hp[(size_t)s * 32];
        accA.x += v.x; accA.y += v.y; accA.z += v.z; accA.w += v.w;
    }
    accA.x += accB.x; accA.y += accB.y; accA.z += accB.z; accA.w += accB.w;
    accA.x += __shfl_down(accA.x, 32);
    accA.y += __shfl_down(accA.y, 32);
    accA.z += __shfl_down(accA.z, 32);
    accA.w += __shfl_down(accA.w, 32);
    if (half == 0) {
        float inv = 1.0f / fmaxf((float)(end - beg), 1.0f);
        uint2 o;
        o.x = (unsigned)f32_to_bf16(accA.x * inv) | ((unsigned)f32_to_bf16(accA.y * inv) << 16);
        o.y = (unsigned)f32_to_bf16(accA.z * inv) | ((unsigned)f32_to_bf16(accA.w * inv) << 16);
        ((uint2*)out)[(size_t)row * 32 + fl] = o;
    }
}

// ---------------- gather, feat=256 bf16 src -> bf16 out ----------------
__global__ void sage_gather256(const unsigned short* __restrict__ h, const int* __restrict__ csr,
                               const int* __restrict__ off, unsigned short* __restrict__ out,
                               int n_dst) {
    int row = (blockIdx.x * 256 + threadIdx.x) >> 6;
    if (row >= n_dst) return;
    const int lane = threadIdx.x & 63;
    const int half = lane >> 5;
    const int fl = lane & 31;
    const int beg = off[row], end = off[row + 1];
    const uint4* hp = (const uint4*)h + fl;    // 32 uint4 (8 bf16) per row
    float a[8] = {0.f, 0.f, 0.f, 0.f, 0.f, 0.f, 0.f, 0.f};
    float b[8] = {0.f, 0.f, 0.f, 0.f, 0.f, 0.f, 0.f, 0.f};
    int i = beg;
    for (; i + 3 < end; i += 4) {
        int s0 = csr[i + half];
        int s1 = csr[i + 2 + half];
        uint4 u0 = hp[(size_t)s0 * 32];
        uint4 u1 = hp[(size_t)s1 * 32];
        a[0] += bf16lo(u0.x); a[1] += bf16hi(u0.x);
        a[2] += bf16lo(u0.y); a[3] += bf16hi(u0.y);
        a[4] += bf16lo(u0.z); a[5] += bf16hi(u0.z);
        a[6] += bf16lo(u0.w); a[7] += bf16hi(u0.w);
        b[0] += bf16lo(u1.x); b[1] += bf16hi(u1.x);
        b[2] += bf16lo(u1.y); b[3] += bf16hi(u1.y);
        b[4] += bf16lo(u1.z); b[5] += bf16hi(u1.z);
        b[6] += bf16lo(u1.w); b[7] += bf16hi(u1.w);
    }
    for (; i + 1 < end; i += 2) {
        int s = csr[i + half];
        uint4 u = hp[(size_t)s * 32];
        a[0] += bf16lo(u.x); a[1] += bf16hi(u.x);
        a[2] += bf16lo(u.y); a[3] += bf16hi(u.y);
        a[4] += bf16lo(u.z); a[5] += bf16hi(u.z);
        a[6] += bf16lo(u.w); a[7] += bf16hi(u.w);
    }
    if (i < end && half == 0) {
        int s = csr[i];
        uint4 u = hp[(size_t)s * 32];
        a[0] += bf16lo(u.x); a[1] += bf16hi(u.x);
        a[2] += bf16lo(u.y); a[3] += bf16hi(u.y);
        a[4] += bf16lo(u.z); a[5] += bf16hi(u.z);
        a[6] += bf16lo(u.w); a[7] += bf16hi(u.w);
    }
#pragma unroll
    for (int k = 0; k < 8; ++k) { a[k] += b[k]; a[k] += __shfl_down(a[k], 32); }
    if (half == 0) {
        float inv = 1.0f / fmaxf((float)(end - beg), 1.0f);
        uint4 o;
        o.x = (unsigned)f32_to_bf16(a[0] * inv) | ((unsigned)f32_to_bf16(a[1] * inv) << 16);
        o.y = (unsigned)f32_to_bf16(a[2] * inv) | ((unsigned)f32_to_bf16(a[3] * inv) << 16);
        o.z = (unsigned)f32_to_bf16(a[4] * inv) | ((unsigned)f32_to_bf16(a[5] * inv) << 16);
        o.w = (unsigned)f32_to_bf16(a[6] * inv) | ((unsigned)f32_to_bf16(a[7] * inv) << 16);
        ((uint4*)out)[(size_t)row * 32 + fl] = o;
    }
}

// ---------------- bf16 MFMA GEMM: 128x128 block tile, BK=64 ----------------
// Out[M x N] = act( [Hdst | Hneigh] @ WT^T + b ); 2x2 waves, wave tile 64x64,
// 32 MFMA + 16 ds_read_b128 per ktile (2 barriers). LDS stride 72 shorts:
// fragment reads 2-way bank aliased max (free, m136). Requires K1 % 64 == 0.
// For OUT_BF16 && N==256: epilogue repacks C through LDS -> coalesced dwordx4.
template <int RELU, int OUT_BF16>
__launch_bounds__(256)
__global__ void sage_gemm(const unsigned short* __restrict__ Hdst,
                          const unsigned short* __restrict__ Hneigh,
                          const unsigned short* __restrict__ WT,  // [N][2K1]
                          const float* __restrict__ bias,
                          void* __restrict__ Out,
                          int N, int K1) {
    const int Ktot = 2 * K1;
    __shared__ unsigned short smem[2][128][72];   // 36.9 KB total
    unsigned short (*As)[72] = smem[0];
    unsigned short (*Bs)[72] = smem[1];

    const int t = threadIdx.x;
    const int lane = t & 63;
    const int w = t >> 6;
    const int wm = (w >> 1) * 64;
    const int wn = (w & 1) * 64;
    const int bm = blockIdx.y * 128;
    const int bn = blockIdx.x * 128;

    const int rowL = t >> 1;          // 0..127 staging row
    const int kL = (t & 1) * 32;      // 0 or 32 (four uint4 each)

    f32x4 acc[4][4] = {};

    const int ktiles = Ktot >> 6;     // BK=64
    for (int kt = 0; kt < ktiles; ++kt) {
        const int k0 = kt << 6;
        {   // A: 128 rows x 64 k, 4 uint4 per thread
            const unsigned short* src = (k0 < K1)
                ? (Hdst + (size_t)(bm + rowL) * K1 + k0 + kL)
                : (Hneigh + (size_t)(bm + rowL) * K1 + (k0 - K1) + kL);
            uint4 v0 = *(const uint4*)src;
            uint4 v1 = *(const uint4*)(src + 8);
            uint4 v2 = *(const uint4*)(src + 16);
            uint4 v3 = *(const uint4*)(src + 24);
            *(uint4*)&As[rowL][kL]      = v0;
            *(uint4*)&As[rowL][kL + 8]  = v1;
            *(uint4*)&As[rowL][kL + 16] = v2;
            *(uint4*)&As[rowL][kL + 24] = v3;
        }
        {   // B: 128 n-rows x 64 k, 4 uint4 per thread
            int n = bn + rowL;
            uint4 v0 = {0,0,0,0}, v1 = {0,0,0,0}, v2 = {0,0,0,0}, v3 = {0,0,0,0};
            if (n < N) {
                const unsigned short* srcB = WT + (size_t)n * Ktot + k0 + kL;
                v0 = *(const uint4*)srcB;
                v1 = *(const uint4*)(srcB + 8);
                v2 = *(const uint4*)(srcB + 16);
                v3 = *(const uint4*)(srcB + 24);
            }
            *(uint4*)&Bs[rowL][kL]      = v0;
            *(uint4*)&Bs[rowL][kL + 8]  = v1;
            *(uint4*)&Bs[rowL][kL + 16] = v2;
            *(uint4*)&Bs[rowL][kL + 24] = v3;
        }
        __syncthreads();

        const int fr = lane & 15;
        const int fk = (lane >> 4) * 8;
#pragma unroll
        for (int ks = 0; ks < 64; ks += 32) {
            bf16x8 av[4], bv[4];
#pragma unroll
            for (int mt = 0; mt < 4; ++mt) av[mt] = *(const bf16x8*)&As[wm + mt * 16 + fr][ks + fk];
#pragma unroll
            for (int nt = 0; nt < 4; ++nt) bv[nt] = *(const bf16x8*)&Bs[wn + nt * 16 + fr][ks + fk];
#pragma unroll
            for (int mt = 0; mt < 4; ++mt)
#pragma unroll
                for (int nt = 0; nt < 4; ++nt)
                    acc[mt][nt] = __builtin_amdgcn_mfma_f32_16x16x32_bf16(av[mt], bv[nt], acc[mt][nt], 0, 0, 0);
        }
        __syncthreads();
    }

    // epilogue: C/D layout col=lane&15, row=(lane>>4)*4+reg  [m89-verified]
    const int quad = lane >> 4;
    const int colL = lane & 15;
    if (OUT_BF16 && N == 256) {
        // repack via LDS (stride 136 shorts), then coalesced dwordx4 stores
        unsigned short* C = (unsigned short*)smem;   // 128 x 136 tile (34.8 KB)
#pragma unroll
        for (int mt = 0; mt < 4; ++mt)
#pragma unroll
            for (int nt = 0; nt < 4; ++nt)
#pragma unroll
                for (int r = 0; r < 4; ++r) {
                    int lrow = wm + mt * 16 + quad * 4 + r;
                    int lcol = wn + nt * 16 + colL;
                    float v = acc[mt][nt][r] + bias[bn + lcol];
                    if (RELU) v = fmaxf(v, 0.0f);
                    C[lrow * 136 + lcol] = f32_to_bf16(v);
                }
        __syncthreads();
        unsigned short* o = (unsigned short*)Out;
#pragma unroll
        for (int c = 0; c < 8; ++c) {
            int chunk = t * 8 + c;
            int row = chunk >> 4, cc = chunk & 15;     // 16 chunks of 8 shorts per row
            uint4 v = *(const uint4*)&C[row * 136 + cc * 8];
            *(uint4*)(o + (size_t)(bm + row) * N + bn + cc * 8) = v;
        }
    } else {
#pragma unroll
        for (int mt = 0; mt < 4; ++mt)
#pragma unroll
            for (int nt = 0; nt < 4; ++nt)
#pragma unroll
                for (int r = 0; r < 4; ++r) {
                    int grow = bm + wm + mt * 16 + quad * 4 + r;
                    int gcol = bn + wn + nt * 16 + colL;
                    if (gcol < N) {
                        float v = acc[mt][nt][r] + bias[gcol];
                        if (RELU) v = fmaxf(v, 0.0f);
                        if (OUT_BF16) ((unsigned short*)Out)[(size_t)grow * N + gcol] = f32_to_bf16(v);
                        else ((float*)Out)[(size_t)grow * N + gcol] = v;
                    }
                }
    }
}

// ---------------- launch ----------------

extern "C" void kernel_launch(void* const* d_in, const int* in_sizes, int n_in,
                              void* d_out, int out_size, void* d_ws, size_t ws_size,
                              hipStream_t stream) {
    const float* x    = (const float*)d_in[0];
    const int* src0 = (const int*)d_in[1];
    const int* dst0 = (const int*)d_in[2];
    const int* src1 = (const int*)d_in[3];
    const int* dst1 = (const int*)d_in[4];
    const int* src2 = (const int*)d_in[5];
    const int* dst2 = (const int*)d_in[6];
    const float* Ws0 = (const float*)d_in[7];
    const float* Wn0 = (const float*)d_in[8];
    const float* b0  = (const float*)d_in[9];
    const float* Ws1 = (const float*)d_in[10];
    const float* Wn1 = (const float*)d_in[11];
    const float* b1  = (const float*)d_in[12];
    const float* Ws2 = (const float*)d_in[13];
    const float* Wn2 = (const float*)d_in[14];
    const float* b2  = (const float*)d_in[15];
    float* out = (float*)d_out;

    char* ws = (char*)d_ws;
    unsigned short* xcast   = (unsigned short*)(ws + 0);          // 13,107,200
    unsigned short* h1      = (unsigned short*)(ws + 13107200);   // 26,214,400
    unsigned short* h2      = (unsigned short*)(ws + 39321600);   //  2,621,440
    unsigned short* hneigh0 = (unsigned short*)(ws + 41943040);   // 13,107,200
    unsigned short* hneigh1 = (unsigned short*)(ws + 55050240);   //  2,621,440
    unsigned short* hneigh2 = (unsigned short*)(ws + 57671680);   //    524,288
    unsigned short* WT0     = (unsigned short*)(ws + 58195968);   //    131,072
    unsigned short* WT1     = (unsigned short*)(ws + 58327040);   //    262,144
    unsigned short* WT2     = (unsigned short*)(ws + 58589184);   //     48,128
    int* counts0 = (int*)(ws + 58637312);                         //    204,800
    int* counts1 = (int*)(ws + 58842112);                         //     20,480
    int* counts2 = (int*)(ws + 58862592);                         //      4,096
    int* off0    = (int*)(ws + 58866688);                         //    204,816
    int* off1    = (int*)(ws + 59071504);                         //     20,496
    int* off2    = (int*)(ws + 59092000);                         //      4,112
    int* cur0    = (int*)(ws + 59096112);                         //    204,800
    int* cur1    = (int*)(ws + 59300912);                         //     20,480
    int* cur2    = (int*)(ws + 59321392);                         //      4,096
    int* csr0    = (int*)(ws + 59325488);                         //  3,072,000
    int* csr1    = (int*)(ws + 62397488);                         //    204,800
    int* csr2    = (int*)(ws + 62602288);                         //     20,480  (end 62,622,768)

    // 0. zero counts0|1|2 (contiguous, 229,376 B) — capturable memset node
    hipMemsetAsync(counts0, 0, 229376, stream);

    // 1. fused prep (cast + weights + hist for all 3 layers)
    sage_prep<<<10482, 256, 0, stream>>>(x, xcast, Ws0, Wn0, Ws1, Wn1, Ws2, Wn2,
                                         WT0, WT1, WT2,
                                         dst0, counts0, dst1, counts1, dst2, counts2);
    // 2-3. scan + fill for all layers
    sage_scan<<<3, 1024, 0, stream>>>(counts0, off0, cur0, counts1, off1, cur1, counts2, off2, cur2);
    sage_fill<<<3220, 256, 0, stream>>>(src0, dst0, cur0, csr0,
                                        src1, dst1, cur1, csr1,
                                        src2, dst2, cur2, csr2);

    // Layer 0: n_dst=51200, K1=128, N=256
    sage_gather0<<<12800, 256, 0, stream>>>(x, csr0, off0, hneigh0, 51200);
    { dim3 g(2, 400); sage_gemm<1, 1><<<g, 256, 0, stream>>>(xcast, hneigh0, WT0, b0, h1, 256, 128); }

    // Layer 1: n_dst=5120, K1=256, N=256
    sage_gather256<<<1280, 256, 0, stream>>>(h1, csr1, off1, hneigh1, 5120);
    { dim3 g(2, 40); sage_gemm<1, 1><<<g, 256, 0, stream>>>(h1, hneigh1, WT1, b1, h2, 256, 256); }

    // Layer 2: n_dst=1024, K1=256, N=47, no relu, fp32 out
    sage_gather256<<<256, 256, 0, stream>>>(h2, csr2, off2, hneigh2, 1024);
    { dim3 g(1, 8); sage_gemm<0, 0><<<g, 256, 0, stream>>>(h2, hneigh2, WT2, b2, out, 47, 256); }
}

// Round 2
// 652.505 us; speedup vs baseline: 1.1035x; 1.1035x over previous
//
#include <hip/hip_runtime.h>

// ---------------------------------------------------------------------------
// GraphSAGE 3-layer forward. Round 7:
//  - scan: 56-block parallel scan with co-resident spin rendezvous (was 3
//    blocks x 7 serial barrier-iterations); device-scope release/acquire
//  - fill/hist: 2 edges per thread (int2 loads)
//  - GEMM: BK=64, LDS 36.9 KB (4 blocks/CU), LDS-repack coalesced epilogue
//  - gather0: 8-edge unroll (4 independent row loads per 32-lane half)
//  Harness floor (2x 215us ws poison + restore) ~470 us of dur_us is fixed.
// ---------------------------------------------------------------------------

typedef __bf16 bf16x8 __attribute__((ext_vector_type(8)));
typedef float f32x4 __attribute__((ext_vector_type(4)));

static __device__ __forceinline__ unsigned short f32_to_bf16(float f) {
    unsigned u = __float_as_uint(f);
    u += 0x7fffu + ((u >> 16) & 1u);   // round-nearest-even
    return (unsigned short)(u >> 16);
}
static __device__ __forceinline__ float bf16lo(unsigned u) { return __uint_as_float(u << 16); }
static __device__ __forceinline__ float bf16hi(unsigned u) { return __uint_as_float(u & 0xffff0000u); }

// ---------------- fused prep: cast x[:51200] to bf16, build WT0/1/2, hist ----
// counts must be pre-zeroed (hipMemsetAsync before this kernel).
__global__ void sage_prep(const float* __restrict__ x, unsigned short* __restrict__ xcast,
                          const float* __restrict__ Ws0, const float* __restrict__ Wn0,
                          const float* __restrict__ Ws1, const float* __restrict__ Wn1,
                          const float* __restrict__ Ws2, const float* __restrict__ Wn2,
                          unsigned short* __restrict__ WT0, unsigned short* __restrict__ WT1,
                          unsigned short* __restrict__ WT2,
                          const int* __restrict__ d0, int* __restrict__ c0,
                          const int* __restrict__ d1, int* __restrict__ c1,
                          const int* __restrict__ d2, int* __restrict__ c2) {
    const int b = blockIdx.x;
    if (b < 6400) {                       // cast: 51200*128 floats, 1 float4/thread
        int i = b * 256 + threadIdx.x;
        float4 v = ((const float4*)x)[i];
        uint2 o;
        o.x = (unsigned)f32_to_bf16(v.x) | ((unsigned)f32_to_bf16(v.y) << 16);
        o.y = (unsigned)f32_to_bf16(v.z) | ((unsigned)f32_to_bf16(v.w) << 16);
        ((uint2*)xcast)[i] = o;
    } else if (b < 6656) {                // WT0: [256][256], K1=128
        int idx = (b - 6400) * 256 + threadIdx.x;
        int n = idx >> 8, k = idx & 255;
        float v = (k < 128) ? Ws0[(size_t)k * 256 + n] : Wn0[(size_t)(k - 128) * 256 + n];
        WT0[idx] = f32_to_bf16(v);
    } else if (b < 7168) {                // WT1: [256][512], K1=256
        int idx = (b - 6656) * 256 + threadIdx.x;
        int n = idx >> 9, k = idx & 511;
        float v = (k < 256) ? Ws1[(size_t)k * 256 + n] : Wn1[(size_t)(k - 256) * 256 + n];
        WT1[idx] = f32_to_bf16(v);
    } else if (b < 7262) {                // WT2: [47][512], K1=256
        int idx = (b - 7168) * 256 + threadIdx.x;
        int n = idx >> 9, k = idx & 511;
        float v = (k < 256) ? Ws2[(size_t)k * 47 + n] : Wn2[(size_t)(k - 256) * 47 + n];
        WT2[idx] = f32_to_bf16(v);
    } else if (b < 8762) {                // hist layer 0 (768000 edges, 2/thread)
        int i = (b - 7262) * 256 + threadIdx.x;
        int2 d = ((const int2*)d0)[i];
        atomicAdd(&c0[d.x], 1);
        atomicAdd(&c0[d.y], 1);
    } else if (b < 8862) {                // hist layer 1 (51200 edges, 2/thread)
        int i = (b - 8762) * 256 + threadIdx.x;
        int2 d = ((const int2*)d1)[i];
        atomicAdd(&c1[d.x], 1);
        atomicAdd(&c1[d.y], 1);
    } else {                              // hist layer 2 (5120 edges, 2/thread)
        int i = (b - 8862) * 256 + threadIdx.x;
        int2 d = ((const int2*)d2)[i];
        atomicAdd(&c2[d.x], 1);
        atomicAdd(&c2[d.y], 1);
    }
}

// ---------------- parallel scan: 56 blocks x 1024 threads, one rendezvous ----
// Block b scans one 1024-chunk: b<50 -> layer0, b<55 -> layer1, b==55 -> layer2.
// Totals published with device-scope release atomics into sync[16+b]; sync[0]
// is the arrival counter (pre-zeroed by memset). 56 blocks x 16 waves = 896
// waves << 8192 capacity, so all blocks are co-resident: spin is safe and does
// not depend on dispatch order.
__launch_bounds__(1024)
__global__ void sage_scan(const int* __restrict__ c0, int* __restrict__ o0, int* __restrict__ u0,
                          const int* __restrict__ c1, int* __restrict__ o1, int* __restrict__ u1,
                          const int* __restrict__ c2, int* __restrict__ o2, int* __restrict__ u2,
                          int* __restrict__ sync) {
    const int b = blockIdx.x;
    const int tid = threadIdx.x;
    const int lane = tid & 63;
    const int wid = tid >> 6;
    const int* counts; int* off; int* cur; int chunk, first, nblk, n;
    if (b < 50)      { counts = c0; off = o0; cur = u0; chunk = b;      first = 0;  nblk = 50; n = 51200; }
    else if (b < 55) { counts = c1; off = o1; cur = u1; chunk = b - 50; first = 50; nblk = 5;  n = 5120;  }
    else             { counts = c2; off = o2; cur = u2; chunk = 0;      first = 55; nblk = 1;  n = 1024;  }

    const int idx = chunk * 1024 + tid;
    const int v = counts[idx];

    int incl = v;
#pragma unroll
    for (int d = 1; d < 64; d <<= 1) {
        int t = __shfl_up(incl, d, 64);
        if (lane >= d) incl += t;
    }

    __shared__ int wsum[16];
    __shared__ int s_base;
    if (lane == 63) wsum[wid] = incl;
    __syncthreads();                              // wsum ready

    if (tid < 64) {
        int s = (lane < 16) ? wsum[lane] : 0;
        int inc = s;
#pragma unroll
        for (int d = 1; d < 16; d <<= 1) {
            int t = __shfl_up(inc, d, 64);
            if (lane >= d) inc += t;
        }
        if (lane < 16) wsum[lane] = inc - s;      // wave-exclusive base (reuse)
        if (lane == 15) {                         // inc == block total
            __hip_atomic_store(&sync[16 + b], inc, __ATOMIC_RELEASE, __HIP_MEMORY_SCOPE_AGENT);
            __hip_atomic_fetch_add(&sync[0], 1, __ATOMIC_RELEASE, __HIP_MEMORY_SCOPE_AGENT);
        }
    }
    if (tid == 0) {                               // rendezvous: all 56 published
        while (__hip_atomic_load(&sync[0], __ATOMIC_ACQUIRE, __HIP_MEMORY_SCOPE_AGENT) < 56)
            __builtin_amdgcn_s_sleep(2);
    }
    __syncthreads();                              // everyone past rendezvous

    if (tid < 64) {                               // base = sum of preceding chunks
        int p = (lane < chunk)
            ? __hip_atomic_load(&sync[16 + first + lane], __ATOMIC_RELAXED, __HIP_MEMORY_SCOPE_AGENT)
            : 0;
#pragma unroll
        for (int d = 32; d >= 1; d >>= 1) p += __shfl_down(p, d, 64);
        if (lane == 0) s_base = p;
    }
    __syncthreads();                              // s_base ready

    const int excl = s_base + wsum[wid] + (incl - v);
    off[idx] = excl;
    cur[idx] = excl;
    if (chunk == nblk - 1 && tid == 1023) off[n] = excl + v;   // layer total
}

// ---------------- fused fill (3 layers, 2 edges/thread) ----------------
__global__ void sage_fill(const int* __restrict__ s0, const int* __restrict__ d0,
                          int* __restrict__ u0, int* __restrict__ r0,
                          const int* __restrict__ s1, const int* __restrict__ d1,
                          int* __restrict__ u1, int* __restrict__ r1,
                          const int* __restrict__ s2, const int* __restrict__ d2,
                          int* __restrict__ u2, int* __restrict__ r2) {
    const int b = blockIdx.x;
    if (b < 1500) {
        int i = b * 256 + threadIdx.x;
        int2 s = ((const int2*)s0)[i];
        int2 d = ((const int2*)d0)[i];
        int p0 = atomicAdd(&u0[d.x], 1);
        int p1 = atomicAdd(&u0[d.y], 1);
        r0[p0] = s.x;
        r0[p1] = s.y;
    } else if (b < 1600) {
        int i = (b - 1500) * 256 + threadIdx.x;
        int2 s = ((const int2*)s1)[i];
        int2 d = ((const int2*)d1)[i];
        int p0 = atomicAdd(&u1[d.x], 1);
        int p1 = atomicAdd(&u1[d.y], 1);
        r1[p0] = s.x;
        r1[p1] = s.y;
    } else {
        int i = (b - 1600) * 256 + threadIdx.x;
        int2 s = ((const int2*)s2)[i];
        int2 d = ((const int2*)d2)[i];
        int p0 = atomicAdd(&u2[d.x], 1);
        int p1 = atomicAdd(&u2[d.y], 1);
        r2[p0] = s.x;
        r2[p1] = s.y;
    }
}

// ---------------- gather, feat=128 fp32 src -> bf16 out ----------------
// One wave per dst row; 32 lanes x float4 cover a row; each half takes up to 4
// edges per iteration (8 row-loads in flight per wave).
__global__ void sage_gather0(const float* __restrict__ x, const int* __restrict__ csr,
                             const int* __restrict__ off, unsigned short* __restrict__ out,
                             int n_dst) {
    int row = (blockIdx.x * 256 + threadIdx.x) >> 6;
    if (row >= n_dst) return;
    const int lane = threadIdx.x & 63;
    const int half = lane >> 5;
    const int fl = lane & 31;
    const int beg = off[row], end = off[row + 1];
    const float4* hp = (const float4*)x + fl;   // lane-fixed column offset
    float4 accA = make_float4(0.f, 0.f, 0.f, 0.f);
    float4 accB = make_float4(0.f, 0.f, 0.f, 0.f);
    int i = beg;
    for (; i + 7 < end; i += 8) {          // half0 {i,i+2,i+4,i+6}, half1 {+1,...}
        int s0 = csr[i + half];
        int s1 = csr[i + 2 + half];
        int s2 = csr[i + 4 + half];
        int s3 = csr[i + 6 + half];
        float4 v0 = hp[(size_t)s0 * 32];
        float4 v1 = hp[(size_t)s1 * 32];
        float4 v2 = hp[(size_t)s2 * 32];
        float4 v3 = hp[(size_t)s3 * 32];
        accA.x += v0.x; accA.y += v0.y; accA.z += v0.z; accA.w += v0.w;
        accB.x += v1.x; accB.y += v1.y; accB.z += v1.z; accB.w += v1.w;
        accA.x += v2.x; accA.y += v2.y; accA.z += v2.z; accA.w += v2.w;
        accB.x += v3.x; accB.y += v3.y; accB.z += v3.z; accB.w += v3.w;
    }
    for (; i + 1 < end; i += 2) {
        int s = csr[i + half];
        float4 v = hp[(size_t)s * 32];
        accA.x += v.x; accA.y += v.y; accA.z += v.z; accA.w += v.w;
    }
    if (i < end && half == 0) {
        int s = csr[i];
        float4 v = hp[(size_t)s * 32];
        accA.x += v.x; accA.y += v.y; accA.z += v.z; accA.w += v.w;
    }
    accA.x += accB.x; accA.y += accB.y; accA.z += accB.z; accA.w += accB.w;
    accA.x += __shfl_down(accA.x, 32);
    accA.y += __shfl_down(accA.y, 32);
    accA.z += __shfl_down(accA.z, 32);
    accA.w += __shfl_down(accA.w, 32);
    if (half == 0) {
        float inv = 1.0f / fmaxf((float)(end - beg), 1.0f);
        uint2 o;
        o.x = (unsigned)f32_to_bf16(accA.x * inv) | ((unsigned)f32_to_bf16(accA.y * inv) << 16);
        o.y = (unsigned)f32_to_bf16(accA.z * inv) | ((unsigned)f32_to_bf16(accA.w * inv) << 16);
        ((uint2*)out)[(size_t)row * 32 + fl] = o;
    }
}

// ---------------- gather, feat=256 bf16 src -> bf16 out ----------------
__global__ void sage_gather256(const unsigned short* __restrict__ h, const int* __restrict__ csr,
                               const int* __restrict__ off, unsigned short* __restrict__ out,
                               int n_dst) {
    int row = (blockIdx.x * 256 + threadIdx.x) >> 6;
    if (row >= n_dst) return;
    const int lane = threadIdx.x & 63;
    const int half = lane >> 5;
    const int fl = lane & 31;
    const int beg = off[row], end = off[row + 1];
    const uint4* hp = (const uint4*)h + fl;    // 32 uint4 (8 bf16) per row
    float a[8] = {0.f, 0.f, 0.f, 0.f, 0.f, 0.f, 0.f, 0.f};
    float b[8] = {0.f, 0.f, 0.f, 0.f, 0.f, 0.f, 0.f, 0.f};
    int i = beg;
    for (; i + 3 < end; i += 4) {
        int s0 = csr[i + half];
        int s1 = csr[i + 2 + half];
        uint4 u0 = hp[(size_t)s0 * 32];
        uint4 u1 = hp[(size_t)s1 * 32];
        a[0] += bf16lo(u0.x); a[1] += bf16hi(u0.x);
        a[2] += bf16lo(u0.y); a[3] += bf16hi(u0.y);
        a[4] += bf16lo(u0.z); a[5] += bf16hi(u0.z);
        a[6] += bf16lo(u0.w); a[7] += bf16hi(u0.w);
        b[0] += bf16lo(u1.x); b[1] += bf16hi(u1.x);
        b[2] += bf16lo(u1.y); b[3] += bf16hi(u1.y);
        b[4] += bf16lo(u1.z); b[5] += bf16hi(u1.z);
        b[6] += bf16lo(u1.w); b[7] += bf16hi(u1.w);
    }
    for (; i + 1 < end; i += 2) {
        int s = csr[i + half];
        uint4 u = hp[(size_t)s * 32];
        a[0] += bf16lo(u.x); a[1] += bf16hi(u.x);
        a[2] += bf16lo(u.y); a[3] += bf16hi(u.y);
        a[4] += bf16lo(u.z); a[5] += bf16hi(u.z);
        a[6] += bf16lo(u.w); a[7] += bf16hi(u.w);
    }
    if (i < end && half == 0) {
        int s = csr[i];
        uint4 u = hp[(size_t)s * 32];
        a[0] += bf16lo(u.x); a[1] += bf16hi(u.x);
        a[2] += bf16lo(u.y); a[3] += bf16hi(u.y);
        a[4] += bf16lo(u.z); a[5] += bf16hi(u.z);
        a[6] += bf16lo(u.w); a[7] += bf16hi(u.w);
    }
#pragma unroll
    for (int k = 0; k < 8; ++k) { a[k] += b[k]; a[k] += __shfl_down(a[k], 32); }
    if (half == 0) {
        float inv = 1.0f / fmaxf((float)(end - beg), 1.0f);
        uint4 o;
        o.x = (unsigned)f32_to_bf16(a[0] * inv) | ((unsigned)f32_to_bf16(a[1] * inv) << 16);
        o.y = (unsigned)f32_to_bf16(a[2] * inv) | ((unsigned)f32_to_bf16(a[3] * inv) << 16);
        o.z = (unsigned)f32_to_bf16(a[4] * inv) | ((unsigned)f32_to_bf16(a[5] * inv) << 16);
        o.w = (unsigned)f32_to_bf16(a[6] * inv) | ((unsigned)f32_to_bf16(a[7] * inv) << 16);
        ((uint4*)out)[(size_t)row * 32 + fl] = o;
    }
}

// ---------------- bf16 MFMA GEMM: 128x128 block tile, BK=64 ----------------
// Out[M x N] = act( [Hdst | Hneigh] @ WT^T + b ); 2x2 waves, wave tile 64x64,
// 32 MFMA + 16 ds_read_b128 per ktile (2 barriers). LDS stride 72 shorts:
// fragment reads 2-way bank aliased max (free, m136). Requires K1 % 64 == 0.
// For OUT_BF16 && N==256: epilogue repacks C through LDS -> coalesced dwordx4.
template <int RELU, int OUT_BF16>
__launch_bounds__(256)
__global__ void sage_gemm(const unsigned short* __restrict__ Hdst,
                          const unsigned short* __restrict__ Hneigh,
                          const unsigned short* __restrict__ WT,  // [N][2K1]
                          const float* __restrict__ bias,
                          void* __restrict__ Out,
                          int N, int K1) {
    const int Ktot = 2 * K1;
    __shared__ unsigned short smem[2][128][72];   // 36.9 KB total
    unsigned short (*As)[72] = smem[0];
    unsigned short (*Bs)[72] = smem[1];

    const int t = threadIdx.x;
    const int lane = t & 63;
    const int w = t >> 6;
    const int wm = (w >> 1) * 64;
    const int wn = (w & 1) * 64;
    const int bm = blockIdx.y * 128;
    const int bn = blockIdx.x * 128;

    const int rowL = t >> 1;          // 0..127 staging row
    const int kL = (t & 1) * 32;      // 0 or 32 (four uint4 each)

    f32x4 acc[4][4] = {};

    const int ktiles = Ktot >> 6;     // BK=64
    for (int kt = 0; kt < ktiles; ++kt) {
        const int k0 = kt << 6;
        {   // A: 128 rows x 64 k, 4 uint4 per thread
            const unsigned short* src = (k0 < K1)
                ? (Hdst + (size_t)(bm + rowL) * K1 + k0 + kL)
                : (Hneigh + (size_t)(bm + rowL) * K1 + (k0 - K1) + kL);
            uint4 v0 = *(const uint4*)src;
            uint4 v1 = *(const uint4*)(src + 8);
            uint4 v2 = *(const uint4*)(src + 16);
            uint4 v3 = *(const uint4*)(src + 24);
            *(uint4*)&As[rowL][kL]      = v0;
            *(uint4*)&As[rowL][kL + 8]  = v1;
            *(uint4*)&As[rowL][kL + 16] = v2;
            *(uint4*)&As[rowL][kL + 24] = v3;
        }
        {   // B: 128 n-rows x 64 k, 4 uint4 per thread
            int n = bn + rowL;
            uint4 v0 = {0,0,0,0}, v1 = {0,0,0,0}, v2 = {0,0,0,0}, v3 = {0,0,0,0};
            if (n < N) {
                const unsigned short* srcB = WT + (size_t)n * Ktot + k0 + kL;
                v0 = *(const uint4*)srcB;
                v1 = *(const uint4*)(srcB + 8);
                v2 = *(const uint4*)(srcB + 16);
                v3 = *(const uint4*)(srcB + 24);
            }
            *(uint4*)&Bs[rowL][kL]      = v0;
            *(uint4*)&Bs[rowL][kL + 8]  = v1;
            *(uint4*)&Bs[rowL][kL + 16] = v2;
            *(uint4*)&Bs[rowL][kL + 24] = v3;
        }
        __syncthreads();

        const int fr = lane & 15;
        const int fk = (lane >> 4) * 8;
#pragma unroll
        for (int ks = 0; ks < 64; ks += 32) {
            bf16x8 av[4], bv[4];
#pragma unroll
            for (int mt = 0; mt < 4; ++mt) av[mt] = *(const bf16x8*)&As[wm + mt * 16 + fr][ks + fk];
#pragma unroll
            for (int nt = 0; nt < 4; ++nt) bv[nt] = *(const bf16x8*)&Bs[wn + nt * 16 + fr][ks + fk];
#pragma unroll
            for (int mt = 0; mt < 4; ++mt)
#pragma unroll
                for (int nt = 0; nt < 4; ++nt)
                    acc[mt][nt] = __builtin_amdgcn_mfma_f32_16x16x32_bf16(av[mt], bv[nt], acc[mt][nt], 0, 0, 0);
        }
        __syncthreads();
    }

    // epilogue: C/D layout col=lane&15, row=(lane>>4)*4+reg  [m89-verified]
    const int quad = lane >> 4;
    const int colL = lane & 15;
    if (OUT_BF16 && N == 256) {
        // repack via LDS (stride 136 shorts), then coalesced dwordx4 stores
        unsigned short* C = (unsigned short*)smem;   // 128 x 136 tile (34.8 KB)
#pragma unroll
        for (int mt = 0; mt < 4; ++mt)
#pragma unroll
            for (int nt = 0; nt < 4; ++nt)
#pragma unroll
                for (int r = 0; r < 4; ++r) {
                    int lrow = wm + mt * 16 + quad * 4 + r;
                    int lcol = wn + nt * 16 + colL;
                    float v = acc[mt][nt][r] + bias[bn + lcol];
                    if (RELU) v = fmaxf(v, 0.0f);
                    C[lrow * 136 + lcol] = f32_to_bf16(v);
                }
        __syncthreads();
        unsigned short* o = (unsigned short*)Out;
#pragma unroll
        for (int c = 0; c < 8; ++c) {
            int chunk = t * 8 + c;
            int row = chunk >> 4, cc = chunk & 15;     // 16 chunks of 8 shorts per row
            uint4 v = *(const uint4*)&C[row * 136 + cc * 8];
            *(uint4*)(o + (size_t)(bm + row) * N + bn + cc * 8) = v;
        }
    } else {
#pragma unroll
        for (int mt = 0; mt < 4; ++mt)
#pragma unroll
            for (int nt = 0; nt < 4; ++nt)
#pragma unroll
                for (int r = 0; r < 4; ++r) {
                    int grow = bm + wm + mt * 16 + quad * 4 + r;
                    int gcol = bn + wn + nt * 16 + colL;
                    if (gcol < N) {
                        float v = acc[mt][nt][r] + bias[gcol];
                        if (RELU) v = fmaxf(v, 0.0f);
                        if (OUT_BF16) ((unsigned short*)Out)[(size_t)grow * N + gcol] = f32_to_bf16(v);
                        else ((float*)Out)[(size_t)grow * N + gcol] = v;
                    }
                }
    }
}

// ---------------- launch ----------------

extern "C" void kernel_launch(void* const* d_in, const int* in_sizes, int n_in,
                              void* d_out, int out_size, void* d_ws, size_t ws_size,
                              hipStream_t stream) {
    const float* x    = (const float*)d_in[0];
    const int* src0 = (const int*)d_in[1];
    const int* dst0 = (const int*)d_in[2];
    const int* src1 = (const int*)d_in[3];
    const int* dst1 = (const int*)d_in[4];
    const int* src2 = (const int*)d_in[5];
    const int* dst2 = (const int*)d_in[6];
    const float* Ws0 = (const float*)d_in[7];
    const float* Wn0 = (const float*)d_in[8];
    const float* b0  = (const float*)d_in[9];
    const float* Ws1 = (const float*)d_in[10];
    const float* Wn1 = (const float*)d_in[11];
    const float* b1  = (const float*)d_in[12];
    const float* Ws2 = (const float*)d_in[13];
    const float* Wn2 = (const float*)d_in[14];
    const float* b2  = (const float*)d_in[15];
    float* out = (float*)d_out;

    char* ws = (char*)d_ws;
    unsigned short* xcast   = (unsigned short*)(ws + 0);          // 13,107,200
    unsigned short* h1      = (unsigned short*)(ws + 13107200);   // 26,214,400
    unsigned short* h2      = (unsigned short*)(ws + 39321600);   //  2,621,440
    unsigned short* hneigh0 = (unsigned short*)(ws + 41943040);   // 13,107,200
    unsigned short* hneigh1 = (unsigned short*)(ws + 55050240);   //  2,621,440
    unsigned short* hneigh2 = (unsigned short*)(ws + 57671680);   //    524,288
    unsigned short* WT0     = (unsigned short*)(ws + 58195968);   //    131,072
    unsigned short* WT1     = (unsigned short*)(ws + 58327040);   //    262,144
    unsigned short* WT2     = (unsigned short*)(ws + 58589184);   //     48,128
    int* counts0 = (int*)(ws + 58637312);                         //    204,800
    int* counts1 = (int*)(ws + 58842112);                         //     20,480
    int* counts2 = (int*)(ws + 58862592);                         //      4,096
    int* syncp   = (int*)(ws + 58866688);                         //      4,096 (done + partials)
    int* off0    = (int*)(ws + 58870784);                         //    204,816
    int* off1    = (int*)(ws + 59075600);                         //     20,496
    int* off2    = (int*)(ws + 59096096);                         //      4,112
    int* cur0    = (int*)(ws + 59100208);                         //    204,800
    int* cur1    = (int*)(ws + 59305008);                         //     20,480
    int* cur2    = (int*)(ws + 59325488);                         //      4,096
    int* csr0    = (int*)(ws + 59329584);                         //  3,072,000
    int* csr1    = (int*)(ws + 62401584);                         //    204,800
    int* csr2    = (int*)(ws + 62606384);                         //     20,480  (end 62,626,864)

    // 0. zero counts0|1|2 + sync area (contiguous, 233,472 B) — capturable memset
    hipMemsetAsync(counts0, 0, 233472, stream);

    // 1. fused prep (cast + weights + hist for all 3 layers)
    sage_prep<<<8872, 256, 0, stream>>>(x, xcast, Ws0, Wn0, Ws1, Wn1, Ws2, Wn2,
                                        WT0, WT1, WT2,
                                        dst0, counts0, dst1, counts1, dst2, counts2);
    // 2-3. parallel scan + fill for all layers
    sage_scan<<<56, 1024, 0, stream>>>(counts0, off0, cur0, counts1, off1, cur1,
                                       counts2, off2, cur2, syncp);
    sage_fill<<<1610, 256, 0, stream>>>(src0, dst0, cur0, csr0,
                                        src1, dst1, cur1, csr1,
                                        src2, dst2, cur2, csr2);

    // Layer 0: n_dst=51200, K1=128, N=256
    sage_gather0<<<12800, 256, 0, stream>>>(x, csr0, off0, hneigh0, 51200);
    { dim3 g(2, 400); sage_gemm<1, 1><<<g, 256, 0, stream>>>(xcast, hneigh0, WT0, b0, h1, 256, 128); }

    // Layer 1: n_dst=5120, K1=256, N=256
    sage_gather256<<<1280, 256, 0, stream>>>(h1, csr1, off1, hneigh1, 5120);
    { dim3 g(2, 40); sage_gemm<1, 1><<<g, 256, 0, stream>>>(h1, hneigh1, WT1, b1, h2, 256, 256); }

    // Layer 2: n_dst=1024, K1=256, N=47, no relu, fp32 out
    sage_gather256<<<256, 256, 0, stream>>>(h2, csr2, off2, hneigh2, 1024);
    { dim3 g(1, 8); sage_gemm<0, 0><<<g, 256, 0, stream>>>(h2, hneigh2, WT2, b2, out, 47, 256); }
}